// Round 17
// baseline (156.367 us; speedup 1.0000x reference)
//
#include <hip/hip_runtime.h>
#include <hip/hip_bf16.h>

// Problem constants (fixed by setup_inputs)
constexpr int B_   = 4;
constexpr int C_   = 256;
constexpr int HF   = 16;
constexpr int WF   = 16;
constexpr int HH   = 512;
constexpr int WW   = 512;
constexpr int NSEG = 1024;
constexpr int FOUT = 192;
constexpr int NCELL = HF * WF;      // 256
constexpr int QC    = 256;          // quad-cell blocks (4 concurrent cells each)
constexpr int QP    = 12;           // quad-gemm_P blocks (4 concurrent roles each)

// -----------------------------------------------------------------------------
// 1D tap weight (1/64ths) of pixel coord v toward cell index cc. Exact ints.
// -----------------------------------------------------------------------------
__device__ __forceinline__ unsigned tapw(int v, int cc) {
    if (v < 0 || v >= 512) return 0u;
    int twov = 2 * v - 31;
    int num  = ((twov % 64) + 64) % 64;
    int iv   = (twov - num) >> 6;
    int v0 = max(iv, 0), v1 = min(iv + 1, 15);
    return (unsigned)((v0 == cc ? 64 - num : 0) + (v1 == cc ? num : 0));
}

// -----------------------------------------------------------------------------
// gemm_P, zero-LDS (R12-verified): P[b][ij][f] = sum_c feat[b][c][ij]*w[f][c]
// role gp in [0,48); 256 lanes <-> ij (coalesced feat); w loads wave-uniform
// (scalar s_load). No LDS, no barriers -> safe to run 4 roles per fat block.
// -----------------------------------------------------------------------------
__device__ void gemm_P_body(int gp, int ij, const float* __restrict__ feat,
                            const float* __restrict__ w, float* __restrict__ P) {
    int b  = gp / 12;
    int f0 = (gp % 12) * 16;
    const float* Fb = feat + (size_t)b * C_ * NCELL + ij;   // stride NCELL over c

    float acc[16] = {};
    for (int c0 = 0; c0 < C_; c0 += 4) {
        float fv0 = Fb[(size_t)(c0 + 0) * NCELL];
        float fv1 = Fb[(size_t)(c0 + 1) * NCELL];
        float fv2 = Fb[(size_t)(c0 + 2) * NCELL];
        float fv3 = Fb[(size_t)(c0 + 3) * NCELL];
        #pragma unroll
        for (int j = 0; j < 16; ++j) {
            float4 wv = *reinterpret_cast<const float4*>(&w[(size_t)(f0 + j) * C_ + c0]);
            acc[j] += fv0 * wv.x + fv1 * wv.y + fv2 * wv.z + fv3 * wv.w;
        }
    }
    float* Pp = P + (size_t)b * NCELL * FOUT + (size_t)ij * FOUT + f0;
    #pragma unroll
    for (int j4 = 0; j4 < 4; ++j4)
        *reinterpret_cast<float4*>(Pp + j4 * 4) =
            make_float4(acc[j4 * 4 + 0], acc[j4 * 4 + 1], acc[j4 * 4 + 2], acc[j4 * 4 + 3]);
}

// -----------------------------------------------------------------------------
// cell body (identical math/structure to R10's proven version, parameterized
// on sub-group id): 64x64 window gather, u32 fixed-point LDS bins, AT store.
// -----------------------------------------------------------------------------
__device__ void cell_body(int cb, int stid, const int* __restrict__ seg,
                          float* __restrict__ segout, float* __restrict__ AT,
                          unsigned* __restrict__ lbin, unsigned* __restrict__ wc) {
    int b    = cb >> 8;
    int cell = cb & 255;
    int cy = cell >> 4, cx = cell & 15;
    int ys = 32 * cy - 16, xs = 32 * cx - 16;

    // segout passthrough load (independent; store later)
    const int4* sv = reinterpret_cast<const int4*>(seg + (size_t)cb * 1024);
    float4*     ov = reinterpret_cast<float4*>(segout + (size_t)cb * 1024);
    int4 pv = sv[stid];

    #pragma unroll
    for (int j = 0; j < 4; ++j) lbin[stid * 4 + j] = 0u;
    if (stid < 64) wc[stid] = tapw(xs + stid, cx);

    // per-thread row weight; 4 clamped unconditional int4 window loads
    int r  = stid >> 2;                // window row 0..63
    int y  = ys + r;
    unsigned wrv = tapw(y, cy);
    int yc = min(max(y, 0), HH - 1);
    int cg = (stid & 3) * 16;
    int x0 = xs + cg;
    int xc = min(max(x0, 0), WW - 16);

    const int4* lrow = reinterpret_cast<const int4*>(seg + (size_t)b * (HH * WW) + (size_t)yc * WW + xc);
    int4 v0 = lrow[0], v1 = lrow[1], v2 = lrow[2], v3 = lrow[3];

    ov[stid] = make_float4((float)pv.x, (float)pv.y, (float)pv.z, (float)pv.w);
    __syncthreads();

    uint4 wa  = *reinterpret_cast<const uint4*>(&wc[cg + 0]);
    uint4 wb  = *reinterpret_cast<const uint4*>(&wc[cg + 4]);
    uint4 wcv = *reinterpret_cast<const uint4*>(&wc[cg + 8]);
    uint4 wd  = *reinterpret_cast<const uint4*>(&wc[cg + 12]);

    atomicAdd(&lbin[v0.x], wrv * wa.x);
    atomicAdd(&lbin[v0.y], wrv * wa.y);
    atomicAdd(&lbin[v0.z], wrv * wa.z);
    atomicAdd(&lbin[v0.w], wrv * wa.w);
    atomicAdd(&lbin[v1.x], wrv * wb.x);
    atomicAdd(&lbin[v1.y], wrv * wb.y);
    atomicAdd(&lbin[v1.z], wrv * wb.z);
    atomicAdd(&lbin[v1.w], wrv * wb.w);
    atomicAdd(&lbin[v2.x], wrv * wcv.x);
    atomicAdd(&lbin[v2.y], wrv * wcv.y);
    atomicAdd(&lbin[v2.z], wrv * wcv.z);
    atomicAdd(&lbin[v2.w], wrv * wcv.w);
    atomicAdd(&lbin[v3.x], wrv * wd.x);
    atomicAdd(&lbin[v3.y], wrv * wd.y);
    atomicAdd(&lbin[v3.z], wrv * wd.z);
    atomicAdd(&lbin[v3.w], wrv * wd.w);
    __syncthreads();

    float4* dst = reinterpret_cast<float4*>(AT + ((size_t)(b * NCELL + cell)) * NSEG);
    constexpr float SCL = 1.0f / 4096.0f;
    dst[stid] = make_float4(lbin[stid * 4 + 0] * SCL, lbin[stid * 4 + 1] * SCL,
                            lbin[stid * 4 + 2] * SCL, lbin[stid * 4 + 3] * SCL);
}

// -----------------------------------------------------------------------------
// Phase 1, fat blocks: 1024 threads = 4 sub-groups of 256.
//   blocks [0,256): 4 CONCURRENT cells (private LDS slices, shared barriers --
//                   per-block critical path = ONE cell, unlike R13's sequential).
//   blocks [256,268): 4 concurrent zero-LDS gemm_P roles.
// 268 blocks ~ 1/CU: the whole grid is resident at once. This isolates
// block-count/dispatch effects from content (DS ops, loads held constant).
// -----------------------------------------------------------------------------
__global__ __launch_bounds__(1024) void k_phase1(const int* __restrict__ seg,
                                                 float* __restrict__ segout,
                                                 float* __restrict__ AT,
                                                 const float* __restrict__ feat,
                                                 const float* __restrict__ w,
                                                 float* __restrict__ P) {
    __shared__ unsigned lbin[4][NSEG];   // 16 KB
    __shared__ unsigned wc[4][64];       // 1 KB
    int blk = blockIdx.x;
    int tid = threadIdx.x;
    int sub = tid >> 8, stid = tid & 255;

    if (blk >= QC) {
        gemm_P_body(((blk - QC) << 2) | sub, stid, feat, w, P);
        return;
    }
    cell_body((blk << 2) | sub, stid, seg, segout, AT, lbin[sub], wc[sub]);
}

// -----------------------------------------------------------------------------
// Pass 2 (R10's proven version): out[s][f] =
// (sum_k AT[b][k][s]*P[b][k][f]) / max(cnt,1) + bias[f]; cnt fused from A reads.
// -----------------------------------------------------------------------------
__global__ __launch_bounds__(256) void k_gemm_out(const float* __restrict__ AT,
                                                  const float* __restrict__ P,
                                                  const float* __restrict__ bias,
                                                  float* __restrict__ out) {
    int ft = blockIdx.x % 3;     // 0..2
    int st = blockIdx.x / 3;     // 0..127
    int b  = st >> 5;
    int s0 = (st & 31) * 32;

    const float* ATb = AT + (size_t)b * NCELL * NSEG;
    const float* Pb  = P  + (size_t)b * NCELL * FOUT;

    __shared__ float As[32][33];
    __shared__ float Ps[32][65];

    int tid = threadIdx.x;
    int tx = tid & 15, ty = tid >> 4;
    float acc[2][4] = {};
    float cnt[2] = {};

    for (int k0 = 0; k0 < NCELL; k0 += 32) {
        {
            int kk = tid >> 3, e4 = (tid & 7) * 4;       // A: 1 float4/thread
            float4 va = *reinterpret_cast<const float4*>(&ATb[(size_t)(k0 + kk) * NSEG + s0 + e4]);
            As[kk][e4 + 0] = va.x; As[kk][e4 + 1] = va.y;
            As[kk][e4 + 2] = va.z; As[kk][e4 + 3] = va.w;
            #pragma unroll
            for (int l = 0; l < 2; ++l) {                // P: 2 float4/thread
                int li = tid * 2 + l;
                int kp = li >> 4, e = (li & 15) * 4;
                float4 vp = *reinterpret_cast<const float4*>(&Pb[(size_t)(k0 + kp) * FOUT + ft * 64 + e]);
                Ps[kp][e + 0] = vp.x; Ps[kp][e + 1] = vp.y;
                Ps[kp][e + 2] = vp.z; Ps[kp][e + 3] = vp.w;
            }
        }
        __syncthreads();
        #pragma unroll
        for (int kk = 0; kk < 32; ++kk) {
            float ar[2], wr[4];
            #pragma unroll
            for (int i = 0; i < 2; ++i) { ar[i] = As[kk][ty * 2 + i]; cnt[i] += ar[i]; }
            #pragma unroll
            for (int j = 0; j < 4; ++j) wr[j] = Ps[kk][tx * 4 + j];
            #pragma unroll
            for (int i = 0; i < 2; ++i)
                #pragma unroll
                for (int j = 0; j < 4; ++j) acc[i][j] += ar[i] * wr[j];
        }
        __syncthreads();
    }

    #pragma unroll
    for (int i = 0; i < 2; ++i) {
        int row = b * NSEG + s0 + ty * 2 + i;
        float rinv = 1.0f / fmaxf(cnt[i], 1.0f);
        #pragma unroll
        for (int j = 0; j < 4; ++j) {
            int f = ft * 64 + tx * 4 + j;
            out[(size_t)row * FOUT + f] = acc[i][j] * rinv + bias[f];
        }
    }
}

extern "C" void kernel_launch(void* const* d_in, const int* in_sizes, int n_in,
                              void* d_out, int out_size, void* d_ws, size_t ws_size,
                              hipStream_t stream) {
    const float* feat = (const float*)d_in[0];   // (4,256,16,16)
    const float* w    = (const float*)d_in[1];   // (192,256)
    const float* bias = (const float*)d_in[2];   // (192,)
    const int*   seg  = (const int*)d_in[3];     // (4,512,512)

    float* out    = (float*)d_out;                          // (4,1024,192)
    float* segout = out + (size_t)B_ * NSEG * FOUT;         // (4,512,512) as float

    // Workspace layout:
    char* wsb = (char*)d_ws;
    float* AT = (float*)wsb;                                // 4*256*1024 f32 = 4 MB
    float* P  = (float*)(wsb + (5u << 20));                 // 4*256*192 f32

    k_phase1  <<<QC + QP, 1024, 0, stream>>>(seg, segout, AT, feat, w, P);
    k_gemm_out<<<(B_ * NSEG / 32) * (FOUT / 64), 256, 0, stream>>>(AT, P, bias, out);
}

// Round 19
// 48.569 us; speedup vs baseline: 3.2195x; 3.2195x over previous
//
#include <hip/hip_runtime.h>
#include <hip/hip_bf16.h>

// Problem constants (fixed by setup_inputs)
constexpr int B_   = 4;
constexpr int C_   = 256;
constexpr int HF   = 16;
constexpr int WF   = 16;
constexpr int HH   = 512;
constexpr int WW   = 512;
constexpr int NSEG = 1024;
constexpr int FOUT = 192;
constexpr int NCELL = HF * WF;      // 256
constexpr int CB    = B_ * NCELL;   // 1024 cell blocks
constexpr int GPB   = 48;           // gemm_P blocks (FIRST in grid)

// -----------------------------------------------------------------------------
// LDS shapes
// -----------------------------------------------------------------------------
struct PS { float Fs[32][65]; float Ws[64][33]; };          // ~16.6 KB

union CellSMem {
    struct { unsigned lbin[NSEG]; unsigned wc[64]; } c;     // 4.25 KB
    PS p;
};

// -----------------------------------------------------------------------------
// gemm_P (256-thread body): P[b][ij][f] = sum_c feat[b][c][ij] * w[f][c]
// M=64(ij) N=64(f) K=256; 4x4 outputs per thread.
// -----------------------------------------------------------------------------
__device__ void gemm_P_body(int gp, const float* __restrict__ feat,
                            const float* __restrict__ w, float* __restrict__ P,
                            PS& sm) {
    int ni = gp % 3;
    int mi = (gp / 3) & 3;
    int b  = gp / 12;
    const float* Fb = feat + (size_t)b * C_ * NCELL;

    int tid = threadIdx.x;
    int tx = tid & 15, ty = tid >> 4;
    float acc[4][4] = {};

    for (int k0 = 0; k0 < C_; k0 += 32) {
        #pragma unroll
        for (int l = 0; l < 2; ++l) {
            int li = tid * 2 + l;            // 0..511
            int kk = li >> 4;                // 0..31
            int m4 = (li & 15) * 4;
            float4 vf = *reinterpret_cast<const float4*>(&Fb[(size_t)(k0 + kk) * NCELL + mi * 64 + m4]);
            sm.Fs[kk][m4 + 0] = vf.x; sm.Fs[kk][m4 + 1] = vf.y;
            sm.Fs[kk][m4 + 2] = vf.z; sm.Fs[kk][m4 + 3] = vf.w;
            int row = li >> 3;               // 0..63
            int kq  = (li & 7) * 4;
            float4 vw = *reinterpret_cast<const float4*>(&w[(size_t)(ni * 64 + row) * C_ + k0 + kq]);
            sm.Ws[row][kq + 0] = vw.x; sm.Ws[row][kq + 1] = vw.y;
            sm.Ws[row][kq + 2] = vw.z; sm.Ws[row][kq + 3] = vw.w;
        }
        __syncthreads();
        #pragma unroll
        for (int kk = 0; kk < 32; ++kk) {
            float ar[4], wr[4];
            #pragma unroll
            for (int i = 0; i < 4; ++i) ar[i] = sm.Fs[kk][ty * 4 + i];
            #pragma unroll
            for (int j = 0; j < 4; ++j) wr[j] = sm.Ws[tx * 4 + j][kk];
            #pragma unroll
            for (int i = 0; i < 4; ++i)
                #pragma unroll
                for (int j = 0; j < 4; ++j) acc[i][j] += ar[i] * wr[j];
        }
        __syncthreads();
    }

    #pragma unroll
    for (int i = 0; i < 4; ++i)
        #pragma unroll
        for (int j = 0; j < 4; ++j)
            P[(size_t)b * NCELL * FOUT + (size_t)(mi * 64 + ty * 4 + i) * FOUT + ni * 64 + tx * 4 + j] = acc[i][j];
}

// -----------------------------------------------------------------------------
// 1D tap weight of coordinate v (pixel) toward cell index cc, in 1/64ths.
// Exact integer arithmetic; OOB v handled by caller (returns 0).
// -----------------------------------------------------------------------------
__device__ __forceinline__ unsigned tapw(int v, int cc) {
    if (v < 0 || v >= 512) return 0u;
    int twov = 2 * v - 31;                 // src*64 = (2v-31) ... exact /64
    int num  = ((twov % 64) + 64) % 64;    // frac in 1/64ths
    int iv   = (twov - num) >> 6;          // floor
    int v0 = max(iv, 0), v1 = min(iv + 1, 15);
    return (unsigned)((v0 == cc ? 64 - num : 0) + (v1 == cc ? num : 0));
}

// -----------------------------------------------------------------------------
// Pass 1: blocks [0,48): gemm_P (launched FIRST so it overlaps the cells).
//         blocks [48,1072): GATHER, fixed-point. One block per (image, cell):
//   64x64 support window. Thread t owns row r=t>>2, 16 px at col (t&3)*16:
//   4 unconditional clamped int4 loads (issued before the barrier, full MLP),
//   row-weight in registers, col-weights via 4 uint4 LDS reads, then 16
//   fire-and-forget ds_add_u32. AT row stored as float/4096 (exact).
// -----------------------------------------------------------------------------
__global__ __launch_bounds__(256) void k_cell(const int* __restrict__ seg,
                                              float* __restrict__ segout,
                                              float* __restrict__ AT,
                                              const float* __restrict__ feat,
                                              const float* __restrict__ w,
                                              float* __restrict__ P) {
    __shared__ CellSMem sm;
    int blk = blockIdx.x;
    if (blk < GPB) { gemm_P_body(blk, feat, w, P, sm.p); return; }

    int cb   = blk - GPB;
    int tid  = threadIdx.x;
    int b    = cb >> 8;
    int cell = cb & 255;
    int cy = cell >> 4, cx = cell & 15;
    int ys = 32 * cy - 16, xs = 32 * cx - 16;

    // segout passthrough load (independent; store later)
    const int4* sv = reinterpret_cast<const int4*>(seg + (size_t)cb * 1024);
    float4*     ov = reinterpret_cast<float4*>(segout + (size_t)cb * 1024);
    int4 pv = sv[tid];

    // zero bins; wc table (u32 weights, window cols 0..63)
    #pragma unroll
    for (int j = 0; j < 4; ++j) sm.c.lbin[tid * 4 + j] = 0u;
    if (tid < 64) sm.c.wc[tid] = tapw(xs + tid, cx);

    // per-thread row weight in regs; 4 clamped unconditional int4 loads
    int r  = tid >> 2;                 // window row 0..63
    int y  = ys + r;
    unsigned wrv = tapw(y, cy);
    int yc = min(max(y, 0), HH - 1);
    int cg = (tid & 3) * 16;           // window col of first pixel
    int x0 = xs + cg;
    int xc = min(max(x0, 0), WW - 16); // 16 px fit, 16B-aligned (mult of 16)

    const int4* lrow = reinterpret_cast<const int4*>(seg + (size_t)b * (HH * WW) + (size_t)yc * WW + xc);
    int4 v0 = lrow[0], v1 = lrow[1], v2 = lrow[2], v3 = lrow[3];

    ov[tid] = make_float4((float)pv.x, (float)pv.y, (float)pv.z, (float)pv.w);
    __syncthreads();

    // col weights (vector LDS reads), then 16 back-to-back atomics
    uint4 wa = *reinterpret_cast<const uint4*>(&sm.c.wc[cg + 0]);
    uint4 wb = *reinterpret_cast<const uint4*>(&sm.c.wc[cg + 4]);
    uint4 wcv = *reinterpret_cast<const uint4*>(&sm.c.wc[cg + 8]);
    uint4 wd = *reinterpret_cast<const uint4*>(&sm.c.wc[cg + 12]);

    atomicAdd(&sm.c.lbin[v0.x], wrv * wa.x);
    atomicAdd(&sm.c.lbin[v0.y], wrv * wa.y);
    atomicAdd(&sm.c.lbin[v0.z], wrv * wa.z);
    atomicAdd(&sm.c.lbin[v0.w], wrv * wa.w);
    atomicAdd(&sm.c.lbin[v1.x], wrv * wb.x);
    atomicAdd(&sm.c.lbin[v1.y], wrv * wb.y);
    atomicAdd(&sm.c.lbin[v1.z], wrv * wb.z);
    atomicAdd(&sm.c.lbin[v1.w], wrv * wb.w);
    atomicAdd(&sm.c.lbin[v2.x], wrv * wcv.x);
    atomicAdd(&sm.c.lbin[v2.y], wrv * wcv.y);
    atomicAdd(&sm.c.lbin[v2.z], wrv * wcv.z);
    atomicAdd(&sm.c.lbin[v2.w], wrv * wcv.w);
    atomicAdd(&sm.c.lbin[v3.x], wrv * wd.x);
    atomicAdd(&sm.c.lbin[v3.y], wrv * wd.y);
    atomicAdd(&sm.c.lbin[v3.z], wrv * wd.z);
    atomicAdd(&sm.c.lbin[v3.w], wrv * wd.w);
    __syncthreads();

    // coalesced row store: AT[b][cell][s] = lbin[s] / 4096  (exact)
    float4* dst = reinterpret_cast<float4*>(AT + ((size_t)(b * NCELL + cell)) * NSEG);
    constexpr float SCL = 1.0f / 4096.0f;
    dst[tid] = make_float4(sm.c.lbin[tid * 4 + 0] * SCL, sm.c.lbin[tid * 4 + 1] * SCL,
                           sm.c.lbin[tid * 4 + 2] * SCL, sm.c.lbin[tid * 4 + 3] * SCL);
}

// -----------------------------------------------------------------------------
// Pass 2: out[s][f] = (sum_k AT[b][k][s]*P[b][k][f]) / max(cnt,1) + bias[f]
// cnt fused from the same LDS reads. M-tile 32 (384 blocks), N=64, K=256.
// -----------------------------------------------------------------------------
__global__ __launch_bounds__(256) void k_gemm_out(const float* __restrict__ AT,
                                                  const float* __restrict__ P,
                                                  const float* __restrict__ bias,
                                                  float* __restrict__ out) {
    int ft = blockIdx.x % 3;     // 0..2
    int st = blockIdx.x / 3;     // 0..127
    int b  = st >> 5;
    int s0 = (st & 31) * 32;

    const float* ATb = AT + (size_t)b * NCELL * NSEG;
    const float* Pb  = P  + (size_t)b * NCELL * FOUT;

    __shared__ float As[32][33];
    __shared__ float Ps[32][65];

    int tid = threadIdx.x;
    int tx = tid & 15, ty = tid >> 4;
    float acc[2][4] = {};
    float cnt[2] = {};

    for (int k0 = 0; k0 < NCELL; k0 += 32) {
        {
            int kk = tid >> 3, e4 = (tid & 7) * 4;       // A: 1 float4/thread
            float4 va = *reinterpret_cast<const float4*>(&ATb[(size_t)(k0 + kk) * NSEG + s0 + e4]);
            As[kk][e4 + 0] = va.x; As[kk][e4 + 1] = va.y;
            As[kk][e4 + 2] = va.z; As[kk][e4 + 3] = va.w;
            #pragma unroll
            for (int l = 0; l < 2; ++l) {                // P: 2 float4/thread
                int li = tid * 2 + l;
                int kp = li >> 4, e = (li & 15) * 4;
                float4 vp = *reinterpret_cast<const float4*>(&Pb[(size_t)(k0 + kp) * FOUT + ft * 64 + e]);
                Ps[kp][e + 0] = vp.x; Ps[kp][e + 1] = vp.y;
                Ps[kp][e + 2] = vp.z; Ps[kp][e + 3] = vp.w;
            }
        }
        __syncthreads();
        #pragma unroll
        for (int kk = 0; kk < 32; ++kk) {
            float ar[2], wr[4];
            #pragma unroll
            for (int i = 0; i < 2; ++i) { ar[i] = As[kk][ty * 2 + i]; cnt[i] += ar[i]; }
            #pragma unroll
            for (int j = 0; j < 4; ++j) wr[j] = Ps[kk][tx * 4 + j];
            #pragma unroll
            for (int i = 0; i < 2; ++i)
                #pragma unroll
                for (int j = 0; j < 4; ++j) acc[i][j] += ar[i] * wr[j];
        }
        __syncthreads();
    }

    #pragma unroll
    for (int i = 0; i < 2; ++i) {
        int row = b * NSEG + s0 + ty * 2 + i;
        float rinv = 1.0f / fmaxf(cnt[i], 1.0f);
        #pragma unroll
        for (int j = 0; j < 4; ++j) {
            int f = ft * 64 + tx * 4 + j;
            out[(size_t)row * FOUT + f] = acc[i][j] * rinv + bias[f];
        }
    }
}

extern "C" void kernel_launch(void* const* d_in, const int* in_sizes, int n_in,
                              void* d_out, int out_size, void* d_ws, size_t ws_size,
                              hipStream_t stream) {
    const float* feat = (const float*)d_in[0];   // (4,256,16,16)
    const float* w    = (const float*)d_in[1];   // (192,256)
    const float* bias = (const float*)d_in[2];   // (192,)
    const int*   seg  = (const int*)d_in[3];     // (4,512,512)

    float* out    = (float*)d_out;                          // (4,1024,192)
    float* segout = out + (size_t)B_ * NSEG * FOUT;         // (4,512,512) as float

    // Workspace layout:
    char* wsb = (char*)d_ws;
    float* AT = (float*)wsb;                                // 4*256*1024 f32 = 4 MB
    float* P  = (float*)(wsb + (5u << 20));                 // 4*256*192 f32

    k_cell    <<<GPB + CB, 256, 0, stream>>>(seg, segout, AT, feat, w, P);
    k_gemm_out<<<(B_ * NSEG / 32) * (FOUT / 64), 256, 0, stream>>>(AT, P, bias, out);
}